// Round 8
// baseline (175.635 us; speedup 1.0000x reference)
//
#include <hip/hip_runtime.h>
#include <stdint.h>

#define BB 8
#define NN 2048
#define KK 32
#define FIN 256
#define FOUT 256
#define CC 512                 // 2*FOUT channels
#define MM (BB*NN)             // 16384 rows
#define RB 32                  // rows per gemm block
#define NBLK (MM/RB)           // 512 gemm blocks
#define LDA 264                // padded LDS row stride (ushorts)

typedef __attribute__((ext_vector_type(8))) short short8;
typedef __attribute__((ext_vector_type(4))) float f32x4;
typedef __attribute__((ext_vector_type(2))) float f32x2;

__device__ __forceinline__ unsigned short f2bf(float f) {
    union { float f; unsigned u; } v; v.f = f;
    unsigned u = v.u;
    return (unsigned short)((u + 0x7FFFu + ((u >> 16) & 1u)) >> 16);  // RNE
}
__device__ __forceinline__ float bf2f(unsigned short s) {
    union { unsigned u; float f; } v; v.u = ((unsigned)s) << 16;
    return v.f;
}
// 2 bf16 in one dword -> float2 {lo, hi}; hi needs no shift (AND only)
__device__ __forceinline__ f32x2 bfpair(unsigned u) {
    union { unsigned u; float f; } lo, hi;
    lo.u = u << 16;
    hi.u = u & 0xFFFF0000u;
    return (f32x2){lo.f, hi.f};
}

// ---------------- K1: W pack (blocks [0,128)) + x->bf16 conv (blocks [128,2176))
__global__ void k_prep(const float* __restrict__ Wx, const float* __restrict__ Wxb,
                       const float* __restrict__ Wn, const float* __restrict__ Wnb,
                       const float* __restrict__ x,
                       unsigned short* __restrict__ Wc, float* __restrict__ bc,
                       unsigned short* __restrict__ xb) {
    const int blk = blockIdx.x;
    const int tid = threadIdx.x;
    if (blk < 128) {            // weight pack + bias concat
        int gid = blk * 256 + tid;                  // 4 elems each
        int e0 = gid * 4;
        int o = e0 >> 8, k = e0 & 255;
        const float* src = (o < FOUT) ? (Wx + o * FIN + k) : (Wn + (o - FOUT) * FIN + k);
        float4 v = *(const float4*)src;
        ushort4 p; p.x = f2bf(v.x); p.y = f2bf(v.y); p.z = f2bf(v.z); p.w = f2bf(v.w);
        *(ushort4*)(Wc + e0) = p;
        if (gid < 128) {
            int c0 = gid * 4;
            float4 bv = (c0 < FOUT) ? *(const float4*)(Wxb + c0)
                                    : *(const float4*)(Wnb + c0 - FOUT);
            *(float4*)(bc + c0) = bv;
        }
    } else {                    // x fp32 -> bf16, 8 elems/thread
        size_t gid = (size_t)(blk - 128) * 256 + tid;
        size_t e0 = gid * 8;
        float4 v0 = *(const float4*)(x + e0);
        float4 v1 = *(const float4*)(x + e0 + 4);
        ushort4 p0, p1;
        p0.x = f2bf(v0.x); p0.y = f2bf(v0.y); p0.z = f2bf(v0.z); p0.w = f2bf(v0.w);
        p1.x = f2bf(v1.x); p1.y = f2bf(v1.y); p1.z = f2bf(v1.z); p1.w = f2bf(v1.w);
        *(ushort4*)(xb + e0)     = p0;
        *(ushort4*)(xb + e0 + 4) = p1;
    }
}

// ---------------- K2: 512 threads (8 waves), RB=32.
// NEW: gather/GEMM overlap. Wave w owns 32 SELF channels (sbg=w*32) and 32
// NEIGHBOR channels (nbg=256+w*32). The self-GEMM (8 K-steps, 4 MFMA each,
// B prefetched one step ahead) is folded into the gather k-loop (one step per
// 2 gather iters) so MFMA/LDS work hides the gather's L2 latency and vice
// versa. Neighbor-GEMM runs after the As[1] barrier. accN init is deferred
// past the gather loop to keep peak VGPR <= 128 (2 blocks/CU).
__global__ __launch_bounds__(512, 4)
void k_gemm(const unsigned short* __restrict__ xb, const int* __restrict__ idx,
            const unsigned short* __restrict__ Wc,
            const float* __restrict__ bc,
            unsigned short* __restrict__ h,
            float* __restrict__ psum, float* __restrict__ psq) {
    __shared__ unsigned short As[2][RB * LDA];   // [0]=self rows, [1]=neighbor rows
    __shared__ float sqpart[8][RB];
    __shared__ float rnorm[RB];

    const int bid  = blockIdx.x;
    const int tid  = threadIdx.x;
    const int w    = tid >> 6;          // 0..7
    const int lane = tid & 63;
    const int quad = lane >> 4;
    const int l16  = lane & 15;
    const int p    = lane >> 5;         // neighbor parity
    const int l32  = lane & 31;         // 8-channel group
    const int b    = bid & 7;
    const int n0   = (bid >> 3) * RB;
    const unsigned short* xbat = xb + (size_t)b * NN * FIN;
    const size_t r0g = (size_t)b * NN + n0;      // global output row base

    {   // self tile: 32 rows x 256 ch bf16 = 1024 uint4; 512 thr x 2
        const uint4* gs = (const uint4*)(xbat + (size_t)n0 * FIN);
        #pragma unroll
        for (int i = 0; i < 2; ++i) {
            int e = tid + i * 512;               // row=e>>5, col8=e&31
            *(uint4*)&As[0][(e >> 5) * LDA + (e & 31) * 8] = gs[e];
        }
    }
    __syncthreads();                             // As[0] ready for self-GEMM

    const int sbg = w * 32;                      // self channel base
    const int nbg = 256 + w * 32;                // neighbor channel base

    f32x4 accS[2][2];
    #pragma unroll
    for (int mt = 0; mt < 2; ++mt)
        #pragma unroll
        for (int nt = 0; nt < 2; ++nt) accS[mt][nt] = (f32x4){0.f, 0.f, 0.f, 0.f};

    const unsigned short* ApS = As[0] + (size_t)l16 * LDA + quad * 8;
    const unsigned short* BpS = Wc + (size_t)(sbg + l16) * FIN + quad * 8;

    // gather state: wave w -> rows w*4..w*4+3
    const int* ip = idx + (n0 + (w << 2)) * KK;
    const unsigned short* xp = xbat + l32 * 8;
    f32x2 ac[4][4];                              // [row][pair of channels]
    #pragma unroll
    for (int rr = 0; rr < 4; ++rr)
        #pragma unroll
        for (int c = 0; c < 4; ++c) ac[rr][c] = (f32x2){0.f, 0.f};

    short8 b0c = *(const short8*)(BpS);          // self B prefetch, k0=0
    short8 b1c = *(const short8*)(BpS + 16 * FIN);

    #pragma unroll
    for (int kp = 0; kp < 8; ++kp) {
        const int kkA = (kp << 2) | p;           // gather iters 2kp, 2kp+1
        const int kkB = kkA + 2;
        // --- issue gather loads (A then B) so they fly under the GEMM step
        int jA0 = ip[0 * KK + kkA], jA1 = ip[1 * KK + kkA];
        int jA2 = ip[2 * KK + kkA], jA3 = ip[3 * KK + kkA];
        uint4 vA0 = *(const uint4*)(xp + (size_t)jA0 * FIN);
        uint4 vA1 = *(const uint4*)(xp + (size_t)jA1 * FIN);
        uint4 vA2 = *(const uint4*)(xp + (size_t)jA2 * FIN);
        uint4 vA3 = *(const uint4*)(xp + (size_t)jA3 * FIN);
        int jB0 = ip[0 * KK + kkB], jB1 = ip[1 * KK + kkB];
        int jB2 = ip[2 * KK + kkB], jB3 = ip[3 * KK + kkB];
        uint4 vB0 = *(const uint4*)(xp + (size_t)jB0 * FIN);
        uint4 vB1 = *(const uint4*)(xp + (size_t)jB1 * FIN);
        uint4 vB2 = *(const uint4*)(xp + (size_t)jB2 * FIN);
        uint4 vB3 = *(const uint4*)(xp + (size_t)jB3 * FIN);
        // --- self-GEMM step kp (independent of the loads above)
        {
            const int k0 = kp * 32;
            short8 a0 = *(const short8*)(ApS + k0);
            short8 a1 = *(const short8*)(ApS + 16 * LDA + k0);
            const int k0n = (kp < 7) ? k0 + 32 : 0;       // dummy reload at end
            short8 b0n = *(const short8*)(BpS + k0n);
            short8 b1n = *(const short8*)(BpS + 16 * FIN + k0n);
            accS[0][0] = __builtin_amdgcn_mfma_f32_16x16x32_bf16(a0, b0c, accS[0][0], 0, 0, 0);
            accS[0][1] = __builtin_amdgcn_mfma_f32_16x16x32_bf16(a0, b1c, accS[0][1], 0, 0, 0);
            accS[1][0] = __builtin_amdgcn_mfma_f32_16x16x32_bf16(a1, b0c, accS[1][0], 0, 0, 0);
            accS[1][1] = __builtin_amdgcn_mfma_f32_16x16x32_bf16(a1, b1c, accS[1][1], 0, 0, 0);
            b0c = b0n; b1c = b1n;
        }
        // --- consume gather loads
        {
            const unsigned* u0 = (const unsigned*)&vA0;
            const unsigned* u1 = (const unsigned*)&vA1;
            const unsigned* u2 = (const unsigned*)&vA2;
            const unsigned* u3 = (const unsigned*)&vA3;
            #pragma unroll
            for (int c = 0; c < 4; ++c) {
                ac[0][c] += bfpair(u0[c]);
                ac[1][c] += bfpair(u1[c]);
                ac[2][c] += bfpair(u2[c]);
                ac[3][c] += bfpair(u3[c]);
            }
        }
        {
            const unsigned* u0 = (const unsigned*)&vB0;
            const unsigned* u1 = (const unsigned*)&vB1;
            const unsigned* u2 = (const unsigned*)&vB2;
            const unsigned* u3 = (const unsigned*)&vB3;
            #pragma unroll
            for (int c = 0; c < 4; ++c) {
                ac[0][c] += bfpair(u0[c]);
                ac[1][c] += bfpair(u1[c]);
                ac[2][c] += bfpair(u2[c]);
                ac[3][c] += bfpair(u3[c]);
            }
        }
    }
    {   // mean finalize: cross-parity reduce + bf16 pack -> As[1]
        const float s = 1.0f / (float)KK;
        #pragma unroll
        for (int rr = 0; rr < 4; ++rr) {
            #pragma unroll
            for (int c = 0; c < 4; ++c) {
                ac[rr][c][0] += __shfl_xor(ac[rr][c][0], 32, 64);
                ac[rr][c][1] += __shfl_xor(ac[rr][c][1], 32, 64);
            }
            if (p == 0) {
                unsigned short o8[8];
                #pragma unroll
                for (int c = 0; c < 4; ++c) {
                    o8[2 * c]     = f2bf(ac[rr][c][0] * s);   // lo = even channel
                    o8[2 * c + 1] = f2bf(ac[rr][c][1] * s);   // hi = odd channel
                }
                *(uint4*)&As[1][((w << 2) + rr) * LDA + l32 * 8] = *(const uint4*)o8;
            }
        }
    }
    __syncthreads();                             // As[1] ready

    // ---- neighbor GEMM (accN init deferred: not live during gather)
    f32x4 accN[2][2];
    #pragma unroll
    for (int mt = 0; mt < 2; ++mt)
        #pragma unroll
        for (int nt = 0; nt < 2; ++nt) accN[mt][nt] = (f32x4){0.f, 0.f, 0.f, 0.f};

    const unsigned short* ApN = As[1] + (size_t)l16 * LDA + quad * 8;
    const unsigned short* BpN = Wc + (size_t)(nbg + l16) * FIN + quad * 8;

    #pragma unroll 2
    for (int k0 = 0; k0 < FIN; k0 += 32) {
        short8 a0 = *(const short8*)(ApN + k0);
        short8 a1 = *(const short8*)(ApN + 16 * LDA + k0);
        short8 bn0 = *(const short8*)(BpN + k0);
        short8 bn1 = *(const short8*)(BpN + 16 * FIN + k0);
        accN[0][0] = __builtin_amdgcn_mfma_f32_16x16x32_bf16(a0, bn0, accN[0][0], 0, 0, 0);
        accN[0][1] = __builtin_amdgcn_mfma_f32_16x16x32_bf16(a0, bn1, accN[0][1], 0, 0, 0);
        accN[1][0] = __builtin_amdgcn_mfma_f32_16x16x32_bf16(a1, bn0, accN[1][0], 0, 0, 0);
        accN[1][1] = __builtin_amdgcn_mfma_f32_16x16x32_bf16(a1, bn1, accN[1][1], 0, 0, 0);
    }

    // bias + per-row sum of squares (C/D layout: col=l16, row=quad*4+reg)
    float bS0 = bc[sbg + l16],      bS1 = bc[sbg + 16 + l16];
    float bN0 = bc[nbg + l16],      bN1 = bc[nbg + 16 + l16];

    float rsq[2][4] = {{0.f,0.f,0.f,0.f},{0.f,0.f,0.f,0.f}};
    #pragma unroll
    for (int mt = 0; mt < 2; ++mt)
        #pragma unroll
        for (int r = 0; r < 4; ++r) {
            float v;
            v = accS[mt][0][r] + bS0; accS[mt][0][r] = v; rsq[mt][r] += v * v;
            v = accS[mt][1][r] + bS1; accS[mt][1][r] = v; rsq[mt][r] += v * v;
            v = accN[mt][0][r] + bN0; accN[mt][0][r] = v; rsq[mt][r] += v * v;
            v = accN[mt][1][r] + bN1; accN[mt][1][r] = v; rsq[mt][r] += v * v;
        }
    #pragma unroll
    for (int off = 1; off < 16; off <<= 1)
        #pragma unroll
        for (int mt = 0; mt < 2; ++mt)
            #pragma unroll
            for (int r = 0; r < 4; ++r)
                rsq[mt][r] += __shfl_xor(rsq[mt][r], off, 64);
    if (l16 == 0) {
        #pragma unroll
        for (int mt = 0; mt < 2; ++mt)
            #pragma unroll
            for (int r = 0; r < 4; ++r)
                sqpart[w][mt * 16 + quad * 4 + r] = rsq[mt][r];
    }
    __syncthreads();
    if (tid < RB) {
        float tot = 0.f;
        #pragma unroll
        for (int i = 0; i < 8; ++i) tot += sqpart[i][tid];
        rnorm[tid] = 1.0f / fmaxf(sqrtf(tot), 1e-12f);
    }
    __syncthreads();

    // normalize + relu + h store (bf16) + channel partials
    float csS[2] = {0.f, 0.f}, cqS[2] = {0.f, 0.f};
    float csN[2] = {0.f, 0.f}, cqN[2] = {0.f, 0.f};
    #pragma unroll
    for (int mt = 0; mt < 2; ++mt) {
        #pragma unroll
        for (int r = 0; r < 4; ++r) {
            int row = mt * 16 + quad * 4 + r;
            float rn = rnorm[row];
            unsigned short* hp = h + (r0g + row) * CC;
            #pragma unroll
            for (int nt = 0; nt < 2; ++nt) {
                float vS = fmaxf(accS[mt][nt][r] * rn, 0.0f);
                hp[sbg + nt * 16 + l16] = f2bf(vS);
                csS[nt] += vS; cqS[nt] += vS * vS;
                float vN = fmaxf(accN[mt][nt][r] * rn, 0.0f);
                hp[nbg + nt * 16 + l16] = f2bf(vN);
                csN[nt] += vN; cqN[nt] += vN * vN;
            }
        }
    }
    #pragma unroll
    for (int off = 16; off < 64; off <<= 1)
        #pragma unroll
        for (int nt = 0; nt < 2; ++nt) {
            csS[nt] += __shfl_xor(csS[nt], off, 64);
            cqS[nt] += __shfl_xor(cqS[nt], off, 64);
            csN[nt] += __shfl_xor(csN[nt], off, 64);
            cqN[nt] += __shfl_xor(cqN[nt], off, 64);
        }
    if (quad == 0) {
        #pragma unroll
        for (int nt = 0; nt < 2; ++nt) {
            int cS = sbg + nt * 16 + l16;
            int cN = nbg + nt * 16 + l16;
            psum[(size_t)cS * NBLK + bid] = csS[nt];
            psq [(size_t)cS * NBLK + bid] = cqS[nt];
            psum[(size_t)cN * NBLK + bid] = csN[nt];
            psq [(size_t)cN * NBLK + bid] = cqN[nt];
        }
    }
}

// ---------------- K3: reduce BN partials (512 per channel) -> scale/shift
__global__ void k_stats(const float* __restrict__ psum, const float* __restrict__ psq,
                        const float* __restrict__ gamma, const float* __restrict__ beta,
                        float* __restrict__ ss) {
    __shared__ float ps[4], pq[4];
    int c = blockIdx.x, t = threadIdx.x;
    float s = psum[(size_t)c * NBLK + t] + psum[(size_t)c * NBLK + 256 + t];
    float q = psq [(size_t)c * NBLK + t] + psq [(size_t)c * NBLK + 256 + t];
    #pragma unroll
    for (int off = 32; off; off >>= 1) { s += __shfl_xor(s, off, 64); q += __shfl_xor(q, off, 64); }
    int w = t >> 6, lane = t & 63;
    if (lane == 0) { ps[w] = s; pq[w] = q; }
    __syncthreads();
    if (t == 0) {
        float S = ps[0] + ps[1] + ps[2] + ps[3];
        float Q = pq[0] + pq[1] + pq[2] + pq[3];
        const float inv = 1.0f / (float)MM;
        float mu  = S * inv;
        float var = fmaxf(Q * inv - mu * mu, 0.0f);
        float sc  = gamma[c] * rsqrtf(var + 1e-5f);
        ss[c]      = sc;
        ss[CC + c] = beta[c] - mu * sc;
    }
}

// ---------------- K4: BN apply, bf16 h -> fp32 out, 8 elems/thread.
__global__ void k_apply(const unsigned short* __restrict__ h,
                        const float* __restrict__ ss,
                        float* __restrict__ out) {
    const int x   = blockIdx.x & 7;              // batch == XCD
    const int j   = blockIdx.x >> 3;             // 4-row group within batch
    const int tid = threadIdx.x;
    const size_t e0 = (size_t)x * ((size_t)NN * CC) + (size_t)j * 2048 + (size_t)tid * 8;
    int c0 = (int)(e0 & (CC - 1));
    uint4 hv = *(const uint4*)(h + e0);          // 8 bf16
    const unsigned short* hs = (const unsigned short*)&hv;
    float4 sc0 = *(const float4*)(ss + c0);
    float4 sc1 = *(const float4*)(ss + c0 + 4);
    float4 sh0 = *(const float4*)(ss + CC + c0);
    float4 sh1 = *(const float4*)(ss + CC + c0 + 4);
    float4 o0, o1;
    o0.x = bf2f(hs[0]) * sc0.x + sh0.x;
    o0.y = bf2f(hs[1]) * sc0.y + sh0.y;
    o0.z = bf2f(hs[2]) * sc0.z + sh0.z;
    o0.w = bf2f(hs[3]) * sc0.w + sh0.w;
    o1.x = bf2f(hs[4]) * sc1.x + sh1.x;
    o1.y = bf2f(hs[5]) * sc1.y + sh1.y;
    o1.z = bf2f(hs[6]) * sc1.z + sh1.z;
    o1.w = bf2f(hs[7]) * sc1.w + sh1.w;
    *(float4*)(out + e0)     = o0;
    *(float4*)(out + e0 + 4) = o1;
}

extern "C" void kernel_launch(void* const* d_in, const int* in_sizes, int n_in,
                              void* d_out, int out_size, void* d_ws, size_t ws_size,
                              hipStream_t stream) {
    const float* x     = (const float*)d_in[0];
    const int*   idx   = (const int*)  d_in[1];
    const float* Wx_w  = (const float*)d_in[2];
    const float* Wx_b  = (const float*)d_in[3];
    const float* Wn_w  = (const float*)d_in[4];
    const float* Wn_b  = (const float*)d_in[5];
    const float* gamma = (const float*)d_in[6];
    const float* beta  = (const float*)d_in[7];
    float* out = (float*)d_out;

    char* p = (char*)d_ws;
    unsigned short* xb = (unsigned short*)p; p += (size_t)MM * FIN * 2;   // 8.4 MB
    unsigned short* Wc = (unsigned short*)p; p += (size_t)CC * FIN * 2;   // 256 KB
    float* bc          = (float*)p;          p += (size_t)CC * 4;         // 2 KB
    unsigned short* h  = (unsigned short*)p; p += (size_t)MM * CC * 2;    // 16.8 MB
    float* psum        = (float*)p;          p += (size_t)CC * NBLK * 4;  // 1 MB
    float* psq         = (float*)p;          p += (size_t)CC * NBLK * 4;  // 1 MB
    float* ss          = (float*)p;          p += (size_t)2 * CC * 4;     // 4 KB

    hipLaunchKernelGGL(k_prep,  dim3(2176), dim3(256), 0, stream,
                       Wx_w, Wx_b, Wn_w, Wn_b, x, Wc, bc, xb);
    hipLaunchKernelGGL(k_gemm,  dim3(NBLK), dim3(512), 0, stream, xb, idx, Wc, bc, h, psum, psq);
    hipLaunchKernelGGL(k_stats, dim3(CC),   dim3(256), 0, stream, psum, psq, gamma, beta, ss);
    hipLaunchKernelGGL(k_apply, dim3(4096), dim3(256), 0, stream, h, ss, out);
}

// Round 9
// 146.287 us; speedup vs baseline: 1.2006x; 1.2006x over previous
//
#include <hip/hip_runtime.h>
#include <stdint.h>

#define BB 8
#define NN 2048
#define KK 32
#define FIN 256
#define FOUT 256
#define CC 512                 // 2*FOUT channels
#define MM (BB*NN)             // 16384 rows
#define RB 16                  // rows per gemm block (halved: more blocks/CU)
#define NBLK (MM/RB)           // 1024 gemm blocks (= 4 per CU capacity)
#define LDA 264                // padded LDS row stride (ushorts)

typedef __attribute__((ext_vector_type(8))) short short8;
typedef __attribute__((ext_vector_type(4))) float f32x4;
typedef __attribute__((ext_vector_type(2))) float f32x2;

__device__ __forceinline__ unsigned short f2bf(float f) {
    union { float f; unsigned u; } v; v.f = f;
    unsigned u = v.u;
    return (unsigned short)((u + 0x7FFFu + ((u >> 16) & 1u)) >> 16);  // RNE
}
__device__ __forceinline__ float bf2f(unsigned short s) {
    union { unsigned u; float f; } v; v.u = ((unsigned)s) << 16;
    return v.f;
}
// 2 bf16 in one dword -> float2 {lo, hi}; hi needs no shift (AND only)
__device__ __forceinline__ f32x2 bfpair(unsigned u) {
    union { unsigned u; float f; } lo, hi;
    lo.u = u << 16;
    hi.u = u & 0xFFFF0000u;
    return (f32x2){lo.f, hi.f};
}

// ---------------- K1: W pack (blocks [0,128)) + x->bf16 conv (blocks [128,2176))
__global__ void k_prep(const float* __restrict__ Wx, const float* __restrict__ Wxb,
                       const float* __restrict__ Wn, const float* __restrict__ Wnb,
                       const float* __restrict__ x,
                       unsigned short* __restrict__ Wc, float* __restrict__ bc,
                       unsigned short* __restrict__ xb) {
    const int blk = blockIdx.x;
    const int tid = threadIdx.x;
    if (blk < 128) {            // weight pack + bias concat
        int gid = blk * 256 + tid;                  // 4 elems each
        int e0 = gid * 4;
        int o = e0 >> 8, k = e0 & 255;
        const float* src = (o < FOUT) ? (Wx + o * FIN + k) : (Wn + (o - FOUT) * FIN + k);
        float4 v = *(const float4*)src;
        ushort4 p; p.x = f2bf(v.x); p.y = f2bf(v.y); p.z = f2bf(v.z); p.w = f2bf(v.w);
        *(ushort4*)(Wc + e0) = p;
        if (gid < 128) {
            int c0 = gid * 4;
            float4 bv = (c0 < FOUT) ? *(const float4*)(Wxb + c0)
                                    : *(const float4*)(Wnb + c0 - FOUT);
            *(float4*)(bc + c0) = bv;
        }
    } else {                    // x fp32 -> bf16, 8 elems/thread
        size_t gid = (size_t)(blk - 128) * 256 + tid;
        size_t e0 = gid * 8;
        float4 v0 = *(const float4*)(x + e0);
        float4 v1 = *(const float4*)(x + e0 + 4);
        ushort4 p0, p1;
        p0.x = f2bf(v0.x); p0.y = f2bf(v0.y); p0.z = f2bf(v0.z); p0.w = f2bf(v0.w);
        p1.x = f2bf(v1.x); p1.y = f2bf(v1.y); p1.z = f2bf(v1.z); p1.w = f2bf(v1.w);
        *(ushort4*)(xb + e0)     = p0;
        *(ushort4*)(xb + e0 + 4) = p1;
    }
}

// ---------------- K2: 512 threads (8 waves), RB=16: self-stage + gather-mean
//                  + MFMA GEMM (1 M-tile/wave) + bias + row L2-norm + ReLU
//                  + bf16 h + BN channel partials.
// RB=16 -> 1024 blocks -> up to 4 blocks/CU co-resident (LDS ~17 KB): blocks
// in different phases overlap (one gathers while another MFMAs) -> hides the
// L2 gather latency that capped round-5 at 29% occupancy.
__global__ __launch_bounds__(512, 4)
void k_gemm(const unsigned short* __restrict__ xb, const int* __restrict__ idx,
            const unsigned short* __restrict__ Wc,
            const float* __restrict__ bc,
            unsigned short* __restrict__ h,
            float* __restrict__ psum, float* __restrict__ psq) {
    __shared__ unsigned short As[2][RB * LDA];   // [0]=self rows, [1]=neighbor rows
    __shared__ float sqpart[8][RB];
    __shared__ float rnorm[RB];

    const int bid  = blockIdx.x;
    const int tid  = threadIdx.x;
    const int w    = tid >> 6;          // 0..7
    const int lane = tid & 63;
    const int quad = lane >> 4;
    const int l16  = lane & 15;
    const int p    = lane >> 5;         // neighbor parity
    const int l32  = lane & 31;         // 8-channel group
    const int b    = bid & 7;
    const int n0   = (bid >> 3) * RB;
    const unsigned short* xbat = xb + (size_t)b * NN * FIN;
    const size_t r0g = (size_t)b * NN + n0;      // global output row base

    {   // self tile: 16 rows x 256 ch bf16 = 512 uint4; 512 thr x 1
        const uint4* gs = (const uint4*)(xbat + (size_t)n0 * FIN);
        int e = tid;                             // row=e>>5 (0..15), col8=e&31
        *(uint4*)&As[0][(e >> 5) * LDA + (e & 31) * 8] = gs[e];
    }
    {   // gather-mean: wave w -> rows w*2..w*2+1; k-outer for cross-row ILP;
        // packed {lo,hi} fp32 accumulation -> v_pk_add_f32
        const int* ip = idx + (n0 + (w << 1)) * KK;    // 2 rows' index lists
        const unsigned short* xp = xbat + l32 * 8;
        f32x2 ac[2][4];                                // [row][pair of channels]
        #pragma unroll
        for (int rr = 0; rr < 2; ++rr)
            #pragma unroll
            for (int c = 0; c < 4; ++c) ac[rr][c] = (f32x2){0.f, 0.f};

        #pragma unroll 2
        for (int k = 0; k < 16; ++k) {
            int kk = (k << 1) | p;
            int j0 = ip[0 * KK + kk];
            int j1 = ip[1 * KK + kk];
            uint4 v0 = *(const uint4*)(xp + (size_t)j0 * FIN);
            uint4 v1 = *(const uint4*)(xp + (size_t)j1 * FIN);
            const unsigned* u0 = (const unsigned*)&v0;
            const unsigned* u1 = (const unsigned*)&v1;
            #pragma unroll
            for (int c = 0; c < 4; ++c) {
                ac[0][c] += bfpair(u0[c]);
                ac[1][c] += bfpair(u1[c]);
            }
        }
        const float s = 1.0f / (float)KK;
        #pragma unroll
        for (int rr = 0; rr < 2; ++rr) {
            #pragma unroll
            for (int c = 0; c < 4; ++c) {
                ac[rr][c][0] += __shfl_xor(ac[rr][c][0], 32, 64);
                ac[rr][c][1] += __shfl_xor(ac[rr][c][1], 32, 64);
            }
            if (p == 0) {
                unsigned short o8[8];
                #pragma unroll
                for (int c = 0; c < 4; ++c) {
                    o8[2 * c]     = f2bf(ac[rr][c][0] * s);   // lo = even channel
                    o8[2 * c + 1] = f2bf(ac[rr][c][1] * s);   // hi = odd channel
                }
                *(uint4*)&As[1][((w << 1) + rr) * LDA + l32 * 8] = *(const uint4*)o8;
            }
        }
    }
    __syncthreads();

    const int half = w >> 2;                     // 0: self, 1: neighbor
    const unsigned short* A = As[half];
    const int cbg = half * 256 + (w & 3) * 64;   // wave's 64 output channels

    f32x4 acc[4];
    #pragma unroll
    for (int nt = 0; nt < 4; ++nt) acc[nt] = (f32x4){0.f, 0.f, 0.f, 0.f};

    const unsigned short* Bp = Wc + (size_t)(cbg + l16) * FIN + quad * 8;  // B^T frag base
    const unsigned short* Ap = A + (size_t)l16 * LDA + quad * 8;

    #pragma unroll 2
    for (int k0 = 0; k0 < FIN; k0 += 32) {
        short8 a0 = *(const short8*)(Ap + k0);
        short8 bfr[4];
        #pragma unroll
        for (int nt = 0; nt < 4; ++nt)
            bfr[nt] = *(const short8*)(Bp + (size_t)nt * 16 * FIN + k0);
        #pragma unroll
        for (int nt = 0; nt < 4; ++nt)
            acc[nt] = __builtin_amdgcn_mfma_f32_16x16x32_bf16(a0, bfr[nt], acc[nt], 0, 0, 0);
    }

    // bias + per-row sum of squares (C/D layout: col=l16, row=quad*4+reg)
    float bcv[4];
    #pragma unroll
    for (int nt = 0; nt < 4; ++nt) bcv[nt] = bc[cbg + nt * 16 + l16];

    float rsq[4] = {0.f, 0.f, 0.f, 0.f};
    #pragma unroll
    for (int nt = 0; nt < 4; ++nt)
        #pragma unroll
        for (int r = 0; r < 4; ++r) {
            float v = acc[nt][r] + bcv[nt];
            acc[nt][r] = v;
            rsq[r] += v * v;
        }
    #pragma unroll
    for (int off = 1; off < 16; off <<= 1)
        #pragma unroll
        for (int r = 0; r < 4; ++r)
            rsq[r] += __shfl_xor(rsq[r], off, 64);
    if (l16 == 0) {
        #pragma unroll
        for (int r = 0; r < 4; ++r)
            sqpart[w][quad * 4 + r] = rsq[r];
    }
    __syncthreads();
    if (tid < RB) {
        float tot = 0.f;
        #pragma unroll
        for (int i = 0; i < 8; ++i) tot += sqpart[i][tid];
        rnorm[tid] = 1.0f / fmaxf(sqrtf(tot), 1e-12f);
    }
    __syncthreads();

    // normalize + relu + h store (bf16) + channel partials
    float csum[4] = {0.f,0.f,0.f,0.f};
    float csq [4] = {0.f,0.f,0.f,0.f};
    #pragma unroll
    for (int r = 0; r < 4; ++r) {
        int row = quad * 4 + r;
        float rn = rnorm[row];
        unsigned short* hp = h + (r0g + row) * CC + cbg + l16;
        #pragma unroll
        for (int nt = 0; nt < 4; ++nt) {
            float v = fmaxf(acc[nt][r] * rn, 0.0f);
            hp[nt * 16] = f2bf(v);
            csum[nt] += v;
            csq [nt] += v * v;
        }
    }
    #pragma unroll
    for (int off = 16; off < 64; off <<= 1)
        #pragma unroll
        for (int nt = 0; nt < 4; ++nt) {
            csum[nt] += __shfl_xor(csum[nt], off, 64);
            csq [nt] += __shfl_xor(csq [nt], off, 64);
        }
    if (quad == 0 && p == 0) {
        #pragma unroll
        for (int nt = 0; nt < 4; ++nt) {
            int c = cbg + nt * 16 + l16;
            psum[(size_t)c * NBLK + bid] = csum[nt];
            psq [(size_t)c * NBLK + bid] = csq [nt];
        }
    }
}

// ---------------- K3: reduce BN partials (1024 per channel) -> scale/shift
__global__ void k_stats(const float* __restrict__ psum, const float* __restrict__ psq,
                        const float* __restrict__ gamma, const float* __restrict__ beta,
                        float* __restrict__ ss) {
    __shared__ float ps[4], pq[4];
    int c = blockIdx.x, t = threadIdx.x;
    const float* sp = psum + (size_t)c * NBLK;
    const float* qp = psq  + (size_t)c * NBLK;
    float s = sp[t] + sp[t + 256] + sp[t + 512] + sp[t + 768];
    float q = qp[t] + qp[t + 256] + qp[t + 512] + qp[t + 768];
    #pragma unroll
    for (int off = 32; off; off >>= 1) { s += __shfl_xor(s, off, 64); q += __shfl_xor(q, off, 64); }
    int w = t >> 6, lane = t & 63;
    if (lane == 0) { ps[w] = s; pq[w] = q; }
    __syncthreads();
    if (t == 0) {
        float S = ps[0] + ps[1] + ps[2] + ps[3];
        float Q = pq[0] + pq[1] + pq[2] + pq[3];
        const float inv = 1.0f / (float)MM;
        float mu  = S * inv;
        float var = fmaxf(Q * inv - mu * mu, 0.0f);
        float sc  = gamma[c] * rsqrtf(var + 1e-5f);
        ss[c]      = sc;
        ss[CC + c] = beta[c] - mu * sc;
    }
}

// ---------------- K4: BN apply, bf16 h -> fp32 out, 8 elems/thread.
__global__ void k_apply(const unsigned short* __restrict__ h,
                        const float* __restrict__ ss,
                        float* __restrict__ out) {
    const int x   = blockIdx.x & 7;              // batch == XCD
    const int j   = blockIdx.x >> 3;             // 4-row group within batch
    const int tid = threadIdx.x;
    const size_t e0 = (size_t)x * ((size_t)NN * CC) + (size_t)j * 2048 + (size_t)tid * 8;
    int c0 = (int)(e0 & (CC - 1));
    uint4 hv = *(const uint4*)(h + e0);          // 8 bf16
    const unsigned short* hs = (const unsigned short*)&hv;
    float4 sc0 = *(const float4*)(ss + c0);
    float4 sc1 = *(const float4*)(ss + c0 + 4);
    float4 sh0 = *(const float4*)(ss + CC + c0);
    float4 sh1 = *(const float4*)(ss + CC + c0 + 4);
    float4 o0, o1;
    o0.x = bf2f(hs[0]) * sc0.x + sh0.x;
    o0.y = bf2f(hs[1]) * sc0.y + sh0.y;
    o0.z = bf2f(hs[2]) * sc0.z + sh0.z;
    o0.w = bf2f(hs[3]) * sc0.w + sh0.w;
    o1.x = bf2f(hs[4]) * sc1.x + sh1.x;
    o1.y = bf2f(hs[5]) * sc1.y + sh1.y;
    o1.z = bf2f(hs[6]) * sc1.z + sh1.z;
    o1.w = bf2f(hs[7]) * sc1.w + sh1.w;
    *(float4*)(out + e0)     = o0;
    *(float4*)(out + e0 + 4) = o1;
}

extern "C" void kernel_launch(void* const* d_in, const int* in_sizes, int n_in,
                              void* d_out, int out_size, void* d_ws, size_t ws_size,
                              hipStream_t stream) {
    const float* x     = (const float*)d_in[0];
    const int*   idx   = (const int*)  d_in[1];
    const float* Wx_w  = (const float*)d_in[2];
    const float* Wx_b  = (const float*)d_in[3];
    const float* Wn_w  = (const float*)d_in[4];
    const float* Wn_b  = (const float*)d_in[5];
    const float* gamma = (const float*)d_in[6];
    const float* beta  = (const float*)d_in[7];
    float* out = (float*)d_out;

    char* p = (char*)d_ws;
    unsigned short* xb = (unsigned short*)p; p += (size_t)MM * FIN * 2;   // 8.4 MB
    unsigned short* Wc = (unsigned short*)p; p += (size_t)CC * FIN * 2;   // 256 KB
    float* bc          = (float*)p;          p += (size_t)CC * 4;         // 2 KB
    unsigned short* h  = (unsigned short*)p; p += (size_t)MM * CC * 2;    // 16.8 MB
    float* psum        = (float*)p;          p += (size_t)CC * NBLK * 4;  // 2 MB
    float* psq         = (float*)p;          p += (size_t)CC * NBLK * 4;  // 2 MB
    float* ss          = (float*)p;          p += (size_t)2 * CC * 4;     // 4 KB

    hipLaunchKernelGGL(k_prep,  dim3(2176), dim3(256), 0, stream,
                       Wx_w, Wx_b, Wn_w, Wn_b, x, Wc, bc, xb);
    hipLaunchKernelGGL(k_gemm,  dim3(NBLK), dim3(512), 0, stream, xb, idx, Wc, bc, h, psum, psq);
    hipLaunchKernelGGL(k_stats, dim3(CC),   dim3(256), 0, stream, psum, psq, gamma, beta, ss);
    hipLaunchKernelGGL(k_apply, dim3(4096), dim3(256), 0, stream, h, ss, out);
}